// Round 1
// baseline (109.241 us; speedup 1.0000x reference)
//
#include <hip/hip_runtime.h>
#include <math.h>

#define NE 8
#define ND 512
#define NB 16384
#define DV (ND / 4)          // float4s per (b, expert) row = 128
#define EPSF 1e-8f

// Kernel 1: M[i][j] = (i==j) ? 1 : sigmoid(corr[i][j])
__global__ void prep_M(const float* __restrict__ corr, float* __restrict__ M) {
    int t = threadIdx.x;
    if (t < NE * NE) {
        int i = t >> 3, j = t & 7;
        float s = 1.0f / (1.0f + expf(-corr[t]));
        M[t] = (i == j) ? 1.0f : s;
    }
}

// Kernel 2: entangled[b,i,:] = sum_j M[i][j] * x[b,j,:]
// One thread per (b, dv) float4 column; handles all 8 experts.
__global__ __launch_bounds__(256) void entangle(const float4* __restrict__ x,
                                                const float* __restrict__ M,
                                                float4* __restrict__ out) {
    __shared__ float sM[NE * NE];
    if (threadIdx.x < NE * NE) sM[threadIdx.x] = M[threadIdx.x];
    __syncthreads();

    int tid = blockIdx.x * blockDim.x + threadIdx.x;   // b*DV + dv
    int b  = tid >> 7;                                  // / DV
    int dv = tid & (DV - 1);
    long base = (long)b * (NE * DV) + dv;               // float4 index of x[b,0,dv]

    float4 xv[NE];
#pragma unroll
    for (int j = 0; j < NE; ++j) xv[j] = x[base + j * DV];

#pragma unroll
    for (int i = 0; i < NE; ++i) {
        float4 acc = make_float4(0.f, 0.f, 0.f, 0.f);
#pragma unroll
        for (int j = 0; j < NE; ++j) {
            float m = sM[i * NE + j];
            acc.x = fmaf(m, xv[j].x, acc.x);
            acc.y = fmaf(m, xv[j].y, acc.y);
            acc.z = fmaf(m, xv[j].z, acc.z);
            acc.w = fmaf(m, xv[j].w, acc.w);
        }
        out[base + i * DV] = acc;
    }
}

// Kernel 3: measure = |sum(entangled[0]^2)| / (E*D + eps), deterministic single block.
__global__ __launch_bounds__(256) void measure_k(const float4* __restrict__ ent,
                                                 float* __restrict__ out_measure) {
    float s = 0.f;
    // entangled[0] = first 8*512 = 4096 floats = 1024 float4
    for (int k = threadIdx.x; k < NE * DV; k += 256) {
        float4 v = ent[k];
        s += v.x * v.x + v.y * v.y + v.z * v.z + v.w * v.w;
    }
    // wave-64 reduce
#pragma unroll
    for (int off = 32; off > 0; off >>= 1) s += __shfl_down(s, off);
    __shared__ float ws[4];
    int lane = threadIdx.x & 63, w = threadIdx.x >> 6;
    if (lane == 0) ws[w] = s;
    __syncthreads();
    if (threadIdx.x == 0) {
        float t = ws[0] + ws[1] + ws[2] + ws[3];
        out_measure[0] = fabsf(t) / ((float)(NE * ND) + EPSF);
    }
}

extern "C" void kernel_launch(void* const* d_in, const int* in_sizes, int n_in,
                              void* d_out, int out_size, void* d_ws, size_t ws_size,
                              hipStream_t stream) {
    const float* x    = (const float*)d_in[0];   // (16384, 8, 512) f32
    const float* corr = (const float*)d_in[1];   // (8, 8) f32
    float* out = (float*)d_out;                  // 16384*8*512 entangled + 1 measure
    float* M   = (float*)d_ws;                   // 64 floats scratch

    prep_M<<<1, 64, 0, stream>>>(corr, M);

    int total_threads = NB * DV;                 // 2,097,152
    entangle<<<total_threads / 256, 256, 0, stream>>>(
        (const float4*)x, M, (float4*)out);

    measure_k<<<1, 256, 0, stream>>>((const float4*)out,
                                     out + (size_t)NB * NE * ND);
}

// Round 3
// 92.245 us; speedup vs baseline: 1.1843x; 1.1843x over previous
//
#include <hip/hip_runtime.h>
#include <math.h>

#define NE 8
#define ND 512
#define NB 16384
#define DV (ND / 4)          // float4s per (b, expert) row = 128

typedef float f32x4 __attribute__((ext_vector_type(4)));

// Fused: entangled[b,i,:] = sum_j M[i][j]*x[b,j,:], M = I + sigmoid(corr)*(1-I)
// plus measure = |sum(entangled[0]^2)| / (E*D + 1e-8), computed by block 0 from
// its own accumulator registers (b==0 lives entirely in block 0, threads 0..127).
__global__ __launch_bounds__(256) void fused_entangle(
        const f32x4* __restrict__ x,
        const float* __restrict__ corr,
        f32x4*       __restrict__ out,
        float*       __restrict__ measure_out) {
    __shared__ float sM[NE * NE];
    if (threadIdx.x < NE * NE) {
        int i = threadIdx.x >> 3, j = threadIdx.x & 7;
        float c = corr[threadIdx.x];
        float s = 1.0f / (1.0f + expf(-c));
        sM[threadIdx.x] = (i == j) ? 1.0f : s;
    }
    __syncthreads();

    int tid = blockIdx.x * 256 + threadIdx.x;   // b*DV + dv
    int b  = tid >> 7;                          // / DV
    long base = (long)b * (NE * DV) + (tid & (DV - 1));

    f32x4 xv[NE];
#pragma unroll
    for (int j = 0; j < NE; ++j)
        xv[j] = __builtin_nontemporal_load(&x[base + j * DV]);

    float ssq = 0.f;
#pragma unroll
    for (int i = 0; i < NE; ++i) {
        f32x4 acc = (f32x4)(0.f);
#pragma unroll
        for (int j = 0; j < NE; ++j) {
            float m = sM[i * NE + j];
            acc = xv[j] * m + acc;   // vector FMA, compiler emits v_fmac_f32 x4
        }
        __builtin_nontemporal_store(acc, &out[base + i * DV]);
        if (b == 0)  // only true for threads 0..127 of block 0
            ssq += acc.x * acc.x + acc.y * acc.y + acc.z * acc.z + acc.w * acc.w;
    }

    if (blockIdx.x == 0) {
        // deterministic block reduce: 64-lane shuffle, then LDS across 4 waves
#pragma unroll
        for (int off = 32; off > 0; off >>= 1)
            ssq += __shfl_down(ssq, off);
        __shared__ float ws[4];
        int lane = threadIdx.x & 63, w = threadIdx.x >> 6;
        if (lane == 0) ws[w] = ssq;
        __syncthreads();
        if (threadIdx.x == 0) {
            float t = ws[0] + ws[1] + ws[2] + ws[3];
            measure_out[0] = fabsf(t) / ((float)(NE * ND) + 1e-8f);
        }
    }
}

extern "C" void kernel_launch(void* const* d_in, const int* in_sizes, int n_in,
                              void* d_out, int out_size, void* d_ws, size_t ws_size,
                              hipStream_t stream) {
    const float* x    = (const float*)d_in[0];   // (16384, 8, 512) f32
    const float* corr = (const float*)d_in[1];   // (8, 8) f32
    float* out = (float*)d_out;                  // entangled flat + 1 measure

    int total_threads = NB * DV;                 // 2,097,152
    fused_entangle<<<total_threads / 256, 256, 0, stream>>>(
        (const f32x4*)x, corr, (f32x4*)out,
        out + (size_t)NB * NE * ND);
}